// Round 5
// baseline (1369.128 us; speedup 1.0000x reference)
//
#include <hip/hip_runtime.h>
#include <math.h>

#define A_W 0.955f
#define B_W 1.3693f
#define INF_W 1e6f
#define HDIM 512
#define WDIM 512
#define NPIX (HDIM*WDIM)
#define NSAMP 16
#define NTOT_F 4194304.0f
#define PF 8   // dB prefetch depth
#define PL 4   // pred/tg prefetch depth

// ws layout (bytes):
//  [0,512):        float acc[128]: [s]=S1_bnd, [16+s]=S2_bnd, [32+s]=inter, [48+s]=totp, [64+s]=mx, [80+s]=focal
//  [512,768):      int flags[64]: [0..15]=has_b[s], [16..31]=has_fg[s]
//  [1024,66560):   int blkflags[16384]   (per seed-wave flags, no atomics)
//  [66560, +16MB): float dA[16][512][512]  (seeds)
//  [+16MB, +32MB): float dB[16][512][512]  (pass-1 intermediate)

// DPP move with INF fill for invalid lanes / masked rows.
//   WAVE_SHR1 (0x138): lane i <- lane i-1  (== __shfl_up 1)
//   WAVE_SHL1 (0x130): lane i <- lane i+1  (== __shfl_down 1)
template<int CTRL, int RMASK>
__device__ __forceinline__ float dpp_mov_inf(float x) {
    return __int_as_float(__builtin_amdgcn_update_dpp(
        __float_as_int(INF_W), __float_as_int(x), CTRL, RMASK, 0xF, false));
}

// Inclusive 64-lane prefix-min, pure VALU (DPP).
__device__ __forceinline__ float wave_prefix_min_incl(float t) {
    t = fminf(t, dpp_mov_inf<0x111,0xF>(t));   // row_shr:1
    t = fminf(t, dpp_mov_inf<0x112,0xF>(t));   // row_shr:2
    t = fminf(t, dpp_mov_inf<0x114,0xF>(t));   // row_shr:4
    t = fminf(t, dpp_mov_inf<0x118,0xF>(t));   // row_shr:8
    t = fminf(t, dpp_mov_inf<0x142,0xA>(t));   // row_bcast:15 -> rows 1,3
    t = fminf(t, dpp_mov_inf<0x143,0xC>(t));   // row_bcast:31 -> rows 2,3
    return t;
}

// One chamfer row-step. prev[] (in: previous row, out: current row result).
__device__ __forceinline__ void row_step(const float* jc, float* prev, const float* drow) {
    float lIn = dpp_mov_inf<0x138,0xF>(prev[7]);  // lane i <- lane i-1, lane0=INF
    float rIn = dpp_mov_inf<0x130,0xF>(prev[0]);  // lane i <- lane i+1, lane63=INF
    float g[8];
#pragma unroll
    for (int i = 0; i < 8; ++i) {
        float up = prev[i] + A_W;
        float ul = ((i == 0) ? lIn : prev[i-1]) + B_W;
        float ur = ((i == 7) ? rIn : prev[i+1]) + B_W;
        g[i] = fminf(fminf(drow[i], up), fminf(ul, ur)) - jc[i];
    }
    float c1[8];
    c1[0] = g[0];
#pragma unroll
    for (int i = 1; i < 8; ++i) c1[i] = fminf(g[i], g[i-1]);
    float c2[8];
    c2[0] = c1[0]; c2[1] = c1[1];
#pragma unroll
    for (int i = 2; i < 8; ++i) c2[i] = fminf(c1[i], c1[i-2]);
    float cj[8];
    cj[0] = c2[0]; cj[1] = c2[1]; cj[2] = c2[2]; cj[3] = c2[3];
#pragma unroll
    for (int i = 4; i < 8; ++i) cj[i] = fminf(c2[i], c2[i-4]);
    float t  = wave_prefix_min_incl(cj[7]);
    float ex = dpp_mov_inf<0x138,0xF>(t);
#pragma unroll
    for (int i = 0; i < 8; ++i) prev[i] = jc[i] + fminf(cj[i], ex);
}

__global__ __launch_bounds__(128) void seed_kernel(const int* __restrict__ tg,
                                                   float* __restrict__ d,
                                                   int* __restrict__ blkflags) {
    const int s = blockIdx.x >> 9;
    const int r = blockIdx.x & 511;
    const int tid = threadIdx.x;
    const int c0 = tid * 4;
    const size_t sb = (size_t)s * NPIX;

    bool fg[6], bg[6];
#pragma unroll
    for (int j = 0; j < 6; ++j) { fg[j] = false; bg[j] = false; }
    int4 center = make_int4(0, 0, 0, 0);
#pragma unroll
    for (int dr = -1; dr <= 1; ++dr) {
        int rr = r + dr;
        if (rr < 0 || rr >= HDIM) continue;
        const int* rowp = tg + sb + (size_t)rr * WDIM;
        int4 cc = *(const int4*)(rowp + c0);
        if (dr == 0) center = cc;
        int vl = (c0 > 0) ? rowp[c0 - 1] : -1;        // -1 => outside grid (excluded)
        int vr = (c0 + 4 < WDIM) ? rowp[c0 + 4] : -1;
        int v[6] = {vl, cc.x, cc.y, cc.z, cc.w, vr};
#pragma unroll
        for (int j = 0; j < 6; ++j) {
            if (v[j] >= 0) { fg[j] = fg[j] || (v[j] != 0); bg[j] = bg[j] || (v[j] == 0); }
        }
    }
    float out[4];
    bool anyb = false;
#pragma unroll
    for (int i = 0; i < 4; ++i) {
        bool f = fg[i] || fg[i + 1] || fg[i + 2];
        bool b = bg[i] || bg[i + 1] || bg[i + 2];
        bool bd = f && b;               // dil==1 && ero==0
        anyb = anyb || bd;
        out[i] = bd ? 0.0f : INF_W;
    }
    bool anyfg = (center.x | center.y | center.z | center.w) != 0;
    *(float4*)(d + sb + (size_t)r * WDIM + c0) = make_float4(out[0], out[1], out[2], out[3]);

    // no atomics: per-wave flag store into blkflags
    int wb = __any((int)anyb)  ? 1 : 0;
    int wf = __any((int)anyfg) ? 2 : 0;
    if ((tid & 63) == 0) blkflags[blockIdx.x * 2 + (tid >> 6)] = wb | wf;
}

// OR-reduce blkflags -> flags. One wave per sample.
__global__ __launch_bounds__(64) void flagreduce_kernel(const int* __restrict__ blkflags,
                                                        int* __restrict__ flags) {
    const int s = blockIdx.x;
    const int lane = threadIdx.x;
    const int4* p = (const int4*)(blkflags + s * 1024);
    int v = 0;
#pragma unroll
    for (int i = 0; i < 4; ++i) {
        int4 e = p[lane + 64 * i];
        v |= e.x | e.y | e.z | e.w;
    }
#pragma unroll
    for (int off = 32; off > 0; off >>= 1) v |= __shfl_xor(v, off);
    if (lane == 0) { flags[s] = v & 1; flags[16 + s] = (v >> 1) & 1; }
}

// PASS 1 (top-down). Reads seeds from dA (or tg), writes rows to dB.
__global__ __launch_bounds__(64) void chamfer1_kernel(const int* __restrict__ tg,
                                                      const float* __restrict__ dA,
                                                      float* __restrict__ dB,
                                                      const int* __restrict__ flags) {
    const int s = blockIdx.x;
    const int lane = threadIdx.x;
    const size_t sb = (size_t)s * NPIX;
    const bool useb = flags[s] != 0;
    const int c0 = lane * 8;

    float jc[8];
#pragma unroll
    for (int i = 0; i < 8; ++i) jc[i] = A_W * (float)(c0 + i);

    float buf[PF][8], prev[8];

    auto load1 = [&](int r, float* dst) {
        if (useb) {
            const float* p = dA + sb + (size_t)r * WDIM + c0;
            float4 a = *(const float4*)p;
            float4 b = *(const float4*)(p + 4);
            dst[0]=a.x; dst[1]=a.y; dst[2]=a.z; dst[3]=a.w;
            dst[4]=b.x; dst[5]=b.y; dst[6]=b.z; dst[7]=b.w;
        } else {
            const int* p = tg + sb + (size_t)r * WDIM + c0;
            int4 a = *(const int4*)p;
            int4 b = *(const int4*)(p + 4);
            dst[0] = (a.x == 0) ? 0.f : INF_W;  dst[1] = (a.y == 0) ? 0.f : INF_W;
            dst[2] = (a.z == 0) ? 0.f : INF_W;  dst[3] = (a.w == 0) ? 0.f : INF_W;
            dst[4] = (b.x == 0) ? 0.f : INF_W;  dst[5] = (b.y == 0) ? 0.f : INF_W;
            dst[6] = (b.z == 0) ? 0.f : INF_W;  dst[7] = (b.w == 0) ? 0.f : INF_W;
        }
    };

#pragma unroll
    for (int i = 0; i < 8; ++i) prev[i] = INF_W;
#pragma unroll
    for (int k = 0; k < PF; ++k) load1(k, buf[k]);

    for (int rb = 0; rb < HDIM; rb += PF) {
#pragma unroll
        for (int k = 0; k < PF; ++k) {
            const int r = rb + k;
            row_step(jc, prev, buf[k]);
            if (r + PF < HDIM) load1(r + PF, buf[k]);
            float* p = dB + sb + (size_t)r * WDIM + c0;
            *(float4*)p       = make_float4(prev[0], prev[1], prev[2], prev[3]);
            *(float4*)(p + 4) = make_float4(prev[4], prev[5], prev[6], prev[7]);
        }
    }
}

// PASS 2 (bottom-up, flipped) + FUSED loss accumulation. Reads dB, pred, tg.
// Writes only per-sample accumulators (one wave per sample, plain stores).
__global__ __launch_bounds__(64) void chamfer2_kernel(const float* __restrict__ dB,
                                                      const float* __restrict__ pred,
                                                      const int* __restrict__ tg,
                                                      float* __restrict__ acc) {
    const int s = blockIdx.x;
    const int lane = threadIdx.x;
    const size_t sb = (size_t)s * NPIX;
    const int c0 = lane * 8;

    float jc[8];
#pragma unroll
    for (int i = 0; i < 8; ++i) jc[i] = A_W * (float)(c0 + i);

    float bufD[PF][8], bufP[PL][8], prev[8];
    int   bufT[PL][8];

    auto loadD = [&](int r, float* dst) {
        int pr = HDIM - 1 - r;
        const float* p = dB + sb + (size_t)pr * WDIM + (WDIM - 8 - c0);
        float4 a = *(const float4*)p;        // phys cols = logical c0+7..c0+4
        float4 b = *(const float4*)(p + 4);  // phys cols = logical c0+3..c0
        dst[7]=a.x; dst[6]=a.y; dst[5]=a.z; dst[4]=a.w;
        dst[3]=b.x; dst[2]=b.y; dst[1]=b.z; dst[0]=b.w;
    };
    auto loadPT = [&](int r, float* dp, int* dt) {
        int pr = HDIM - 1 - r;
        const float* pp = pred + sb + (size_t)pr * WDIM + (WDIM - 8 - c0);
        float4 a = *(const float4*)pp;
        float4 b = *(const float4*)(pp + 4);
        dp[7]=a.x; dp[6]=a.y; dp[5]=a.z; dp[4]=a.w;
        dp[3]=b.x; dp[2]=b.y; dp[1]=b.z; dp[0]=b.w;
        const int* tp = tg + sb + (size_t)pr * WDIM + (WDIM - 8 - c0);
        int4 ta = *(const int4*)tp;
        int4 tb = *(const int4*)(tp + 4);
        dt[7]=ta.x; dt[6]=ta.y; dt[5]=ta.z; dt[4]=ta.w;
        dt[3]=tb.x; dt[2]=tb.y; dt[1]=tb.z; dt[0]=tb.w;
    };

#pragma unroll
    for (int i = 0; i < 8; ++i) prev[i] = INF_W;
    float mx = 0.f, facc = 0.f, s1 = 0.f, s2 = 0.f, iacc = 0.f, pacc = 0.f;
#pragma unroll
    for (int k = 0; k < PF; ++k) loadD(k, bufD[k]);
#pragma unroll
    for (int k = 0; k < PL; ++k) loadPT(k, bufP[k], bufT[k]);

    for (int rb = 0; rb < HDIM; rb += PF) {
#pragma unroll
        for (int k = 0; k < PF; ++k) {
            const int r = rb + k;
            row_step(jc, prev, bufD[k]);
            if (r + PF < HDIM) loadD(r + PF, bufD[k]);
            const int sl = r & (PL - 1);
            // fused loss math on the 8 pixels whose final DT is now in prev[]
#pragma unroll
            for (int i = 0; i < 8; ++i) {
                float x = bufP[sl][i];
                int   ti = bufT[sl][i];
                float dd = prev[i];
                float e = __expf(-fabsf(x));              // exp(-|x|)
                float inv = 1.f / (1.f + e);
                float p = (x >= 0.f) ? inv : (1.f - inv); // sigmoid(x)
                float L = __logf(1.f + e);                // softplus(-|x|)
                bool t1 = ti != 0;
                float fo = t1 ? 0.25f * (1.f - p) * (1.f - p) * (fmaxf(-x, 0.f) + L)
                              : 0.75f * p * p * (fmaxf(x, 0.f) + L);
                facc += fo;
                float base = t1 ? (1.f - p) : p;
                s1 += base;
                s2 += base * dd;
                float tf = t1 ? 1.f : 0.f;
                iacc += tf * p;
                pacc += p + tf;
                mx = fmaxf(mx, dd);
            }
            if (r + PL < HDIM) loadPT(r + PL, bufP[sl], bufT[sl]);
        }
    }

#pragma unroll
    for (int off = 32; off > 0; off >>= 1) {
        facc += __shfl_xor(facc, off);
        s1   += __shfl_xor(s1, off);
        s2   += __shfl_xor(s2, off);
        iacc += __shfl_xor(iacc, off);
        pacc += __shfl_xor(pacc, off);
        mx    = fmaxf(mx, __shfl_xor(mx, off));
    }
    if (lane == 0) {
        acc[s]      = s1;
        acc[16 + s] = s2;
        acc[32 + s] = iacc;
        acc[48 + s] = pacc;
        acc[64 + s] = mx;
        acc[80 + s] = facc;
    }
}

__global__ void final_kernel(const float* __restrict__ acc, const int* __restrict__ flags,
                             const float* __restrict__ lv, float* __restrict__ out) {
    if (threadIdx.x == 0) {
        float fsum = 0.f, bsum = 0.f, dsum = 0.f, isum = 0.f;
        for (int s = 0; s < NSAMP; ++s) {
            fsum += acc[80 + s];
            float S1 = acc[s], S2 = acc[16 + s], mxs = acc[64 + s];
            bool hfg = flags[16 + s] != 0;
            // dist = hfg ? d/mx (mx>0) : 1  =>  sum(base*dist) = hfg ? S2/mx : S1
            float distsum = hfg ? ((mxs > 0.f) ? S2 / fmaxf(mxs, 1e-12f) : 0.f) : S1;
            bsum += S1 + distsum;
            float inter = acc[32 + s];
            float tot   = acc[48 + s];
            dsum += (2.f * inter + 1e-6f) / (tot + 1e-6f);
            isum += (inter + 1e-6f) / (tot - inter + 1e-6f);
        }
        float focal = fsum / NTOT_F;
        float bnd   = bsum / NTOT_F;
        float dice = 1.f - dsum / 16.f;
        float iou  = 1.f - isum / 16.f;
        float l0 = lv[0], l1 = lv[1], l2 = lv[2], l3 = lv[3];
        float total = expf(-l0) * focal + l0 + expf(-l1) * dice + l1
                    + expf(-l2) * bnd  + l2 + expf(-l3) * iou  + l3;
        out[0] = total; out[1] = focal; out[2] = dice; out[3] = bnd; out[4] = iou;
    }
}

extern "C" void kernel_launch(void* const* d_in, const int* in_sizes, int n_in,
                              void* d_out, int out_size, void* d_ws, size_t ws_size,
                              hipStream_t stream) {
    const float* pred = (const float*)d_in[0];
    const int*   tg   = (const int*)d_in[1];
    const float* lv   = (const float*)d_in[2];
    float* out = (float*)d_out;
    char* ws = (char*)d_ws;
    float* acc      = (float*)ws;                 // 128 floats
    int*   flags    = (int*)(ws + 512);           // 64 ints
    int*   blkflags = (int*)(ws + 1024);          // 16384 ints
    float* dA       = (float*)(ws + 66560);       // 16 MB (seeds)
    float* dB       = (float*)(ws + 66560 + (size_t)NSAMP * NPIX * 4);  // 16 MB

    seed_kernel<<<NSAMP * HDIM, 128, 0, stream>>>(tg, dA, blkflags);
    flagreduce_kernel<<<NSAMP, 64, 0, stream>>>(blkflags, flags);
    chamfer1_kernel<<<NSAMP, 64, 0, stream>>>(tg, dA, dB, flags);
    chamfer2_kernel<<<NSAMP, 64, 0, stream>>>(dB, pred, tg, acc);
    final_kernel<<<1, 64, 0, stream>>>(acc, flags, lv, out);
}

// Round 6
// 392.046 us; speedup vs baseline: 3.4923x; 3.4923x over previous
//
#include <hip/hip_runtime.h>
#include <math.h>

#define A_W 0.955f
#define B_W 1.3693f
#define INF_W 1e6f
#define HDIM 512
#define WDIM 512
#define NPIX (HDIM*WDIM)
#define NSAMP 16
#define NTOT_F 4194304.0f
#define PF 8   // load prefetch depth
#define SD 4   // store staging ring depth (breaks store-data WAR hazard)

// ws layout (bytes):
//  [0,256):      float acc[64]: [0]=focal_sum [1]=bnd_sum [2..17]=inter[s] [18..33]=totp[s] [34..49]=mx[s]
//  [512,768):    int flags[64]: [0..15]=has_b[s] [16..31]=has_fg[s]
//  [1024,66560): int blkflags[16384]  (per seed-wave flags, no atomics)
//  [66560, +16MB):  float dA[16][512][512]  (seeds -> final DT)
//  [+16MB, +32MB):  float dB[16][512][512]  (pass-1 intermediate)

// DPP move with INF fill for invalid lanes / masked rows.
//   WAVE_SHR1 (0x138): lane i <- lane i-1  (== __shfl_up 1)
//   WAVE_SHL1 (0x130): lane i <- lane i+1  (== __shfl_down 1)
template<int CTRL, int RMASK>
__device__ __forceinline__ float dpp_mov_inf(float x) {
    return __int_as_float(__builtin_amdgcn_update_dpp(
        __float_as_int(INF_W), __float_as_int(x), CTRL, RMASK, 0xF, false));
}

// Inclusive 64-lane prefix-min, pure VALU (DPP).
__device__ __forceinline__ float wave_prefix_min_incl(float t) {
    t = fminf(t, dpp_mov_inf<0x111,0xF>(t));   // row_shr:1
    t = fminf(t, dpp_mov_inf<0x112,0xF>(t));   // row_shr:2
    t = fminf(t, dpp_mov_inf<0x114,0xF>(t));   // row_shr:4
    t = fminf(t, dpp_mov_inf<0x118,0xF>(t));   // row_shr:8
    t = fminf(t, dpp_mov_inf<0x142,0xA>(t));   // row_bcast:15 -> rows 1,3
    t = fminf(t, dpp_mov_inf<0x143,0xC>(t));   // row_bcast:31 -> rows 2,3
    return t;
}

// One chamfer row-step. prev[] (in: previous row, out: current row result).
__device__ __forceinline__ void row_step(const float* jc, float* prev, const float* drow) {
    float lIn = dpp_mov_inf<0x138,0xF>(prev[7]);  // lane i <- lane i-1, lane0=INF
    float rIn = dpp_mov_inf<0x130,0xF>(prev[0]);  // lane i <- lane i+1, lane63=INF
    float g[8];
#pragma unroll
    for (int i = 0; i < 8; ++i) {
        float up = prev[i] + A_W;
        float ul = ((i == 0) ? lIn : prev[i-1]) + B_W;
        float ur = ((i == 7) ? rIn : prev[i+1]) + B_W;
        g[i] = fminf(fminf(drow[i], up), fminf(ul, ur)) - jc[i];
    }
    float c1[8];
    c1[0] = g[0];
#pragma unroll
    for (int i = 1; i < 8; ++i) c1[i] = fminf(g[i], g[i-1]);
    float c2[8];
    c2[0] = c1[0]; c2[1] = c1[1];
#pragma unroll
    for (int i = 2; i < 8; ++i) c2[i] = fminf(c1[i], c1[i-2]);
    float cj[8];
    cj[0] = c2[0]; cj[1] = c2[1]; cj[2] = c2[2]; cj[3] = c2[3];
#pragma unroll
    for (int i = 4; i < 8; ++i) cj[i] = fminf(c2[i], c2[i-4]);
    float t  = wave_prefix_min_incl(cj[7]);
    float ex = dpp_mov_inf<0x138,0xF>(t);
#pragma unroll
    for (int i = 0; i < 8; ++i) prev[i] = jc[i] + fminf(cj[i], ex);
}

__global__ __launch_bounds__(128) void seed_kernel(const int* __restrict__ tg,
                                                   float* __restrict__ d,
                                                   int* __restrict__ blkflags) {
    const int s = blockIdx.x >> 9;
    const int r = blockIdx.x & 511;
    const int tid = threadIdx.x;
    const int c0 = tid * 4;
    const size_t sb = (size_t)s * NPIX;

    bool fg[6], bg[6];
#pragma unroll
    for (int j = 0; j < 6; ++j) { fg[j] = false; bg[j] = false; }
    int4 center = make_int4(0, 0, 0, 0);
#pragma unroll
    for (int dr = -1; dr <= 1; ++dr) {
        int rr = r + dr;
        if (rr < 0 || rr >= HDIM) continue;
        const int* rowp = tg + sb + (size_t)rr * WDIM;
        int4 cc = *(const int4*)(rowp + c0);
        if (dr == 0) center = cc;
        int vl = (c0 > 0) ? rowp[c0 - 1] : -1;        // -1 => outside grid (excluded)
        int vr = (c0 + 4 < WDIM) ? rowp[c0 + 4] : -1;
        int v[6] = {vl, cc.x, cc.y, cc.z, cc.w, vr};
#pragma unroll
        for (int j = 0; j < 6; ++j) {
            if (v[j] >= 0) { fg[j] = fg[j] || (v[j] != 0); bg[j] = bg[j] || (v[j] == 0); }
        }
    }
    float out[4];
    bool anyb = false;
#pragma unroll
    for (int i = 0; i < 4; ++i) {
        bool f = fg[i] || fg[i + 1] || fg[i + 2];
        bool b = bg[i] || bg[i + 1] || bg[i + 2];
        bool bd = f && b;               // dil==1 && ero==0
        anyb = anyb || bd;
        out[i] = bd ? 0.0f : INF_W;
    }
    bool anyfg = (center.x | center.y | center.z | center.w) != 0;
    *(float4*)(d + sb + (size_t)r * WDIM + c0) = make_float4(out[0], out[1], out[2], out[3]);

    int wb = __any((int)anyb)  ? 1 : 0;
    int wf = __any((int)anyfg) ? 2 : 0;
    if ((tid & 63) == 0) blkflags[blockIdx.x * 2 + (tid >> 6)] = wb | wf;
}

// OR-reduce blkflags -> flags. One wave per sample.
__global__ __launch_bounds__(64) void flagreduce_kernel(const int* __restrict__ blkflags,
                                                        int* __restrict__ flags) {
    const int s = blockIdx.x;
    const int lane = threadIdx.x;
    const int4* p = (const int4*)(blkflags + s * 1024);
    int v = 0;
#pragma unroll
    for (int i = 0; i < 4; ++i) {
        int4 e = p[lane + 64 * i];
        v |= e.x | e.y | e.z | e.w;
    }
#pragma unroll
    for (int off = 32; off > 0; off >>= 1) v |= __shfl_xor(v, off);
    if (lane == 0) { flags[s] = v & 1; flags[16 + s] = (v >> 1) & 1; }
}

// PASS 1 (top-down). Reads seeds from dA (or tg), writes rows to dB via staging ring.
__global__ __launch_bounds__(64) void chamfer1_kernel(const int* __restrict__ tg,
                                                      const float* __restrict__ dA,
                                                      float* __restrict__ dB,
                                                      const int* __restrict__ flags) {
    const int s = blockIdx.x;
    const int lane = threadIdx.x;
    const size_t sb = (size_t)s * NPIX;
    const bool useb = flags[s] != 0;
    const int c0 = lane * 8;

    float jc[8];
#pragma unroll
    for (int i = 0; i < 8; ++i) jc[i] = A_W * (float)(c0 + i);

    float buf[PF][8], prev[8], st[SD][8];

    auto load1 = [&](int r, float* dst) {
        if (useb) {
            const float* p = dA + sb + (size_t)r * WDIM + c0;
            float4 a = *(const float4*)p;
            float4 b = *(const float4*)(p + 4);
            dst[0]=a.x; dst[1]=a.y; dst[2]=a.z; dst[3]=a.w;
            dst[4]=b.x; dst[5]=b.y; dst[6]=b.z; dst[7]=b.w;
        } else {
            const int* p = tg + sb + (size_t)r * WDIM + c0;
            int4 a = *(const int4*)p;
            int4 b = *(const int4*)(p + 4);
            dst[0] = (a.x == 0) ? 0.f : INF_W;  dst[1] = (a.y == 0) ? 0.f : INF_W;
            dst[2] = (a.z == 0) ? 0.f : INF_W;  dst[3] = (a.w == 0) ? 0.f : INF_W;
            dst[4] = (b.x == 0) ? 0.f : INF_W;  dst[5] = (b.y == 0) ? 0.f : INF_W;
            dst[6] = (b.z == 0) ? 0.f : INF_W;  dst[7] = (b.w == 0) ? 0.f : INF_W;
        }
    };

#pragma unroll
    for (int i = 0; i < 8; ++i) prev[i] = INF_W;
#pragma unroll
    for (int k = 0; k < PF; ++k) load1(k, buf[k]);

    for (int rb = 0; rb < HDIM; rb += PF) {
#pragma unroll
        for (int k = 0; k < PF; ++k) {
            const int r = rb + k;
            row_step(jc, prev, buf[k]);
            if (r + PF < HDIM) load1(r + PF, buf[k]);
            // stage result; store from ring so prev[] can be overwritten next step
            float* sg = st[r & (SD - 1)];
#pragma unroll
            for (int i = 0; i < 8; ++i) sg[i] = prev[i];
            float* p = dB + sb + (size_t)r * WDIM + c0;
            *(float4*)p       = make_float4(sg[0], sg[1], sg[2], sg[3]);
            *(float4*)(p + 4) = make_float4(sg[4], sg[5], sg[6], sg[7]);
        }
    }
}

// PASS 2 (bottom-up, flipped). Reads dB, writes final DT to dA via staging ring; per-sample max.
__global__ __launch_bounds__(64) void chamfer2_kernel(const float* __restrict__ dB,
                                                      float* __restrict__ dA,
                                                      float* __restrict__ acc) {
    const int s = blockIdx.x;
    const int lane = threadIdx.x;
    const size_t sb = (size_t)s * NPIX;
    const int c0 = lane * 8;

    float jc[8];
#pragma unroll
    for (int i = 0; i < 8; ++i) jc[i] = A_W * (float)(c0 + i);

    float buf[PF][8], prev[8], st[SD][8];

    auto load2 = [&](int r, float* dst) {
        int pr = HDIM - 1 - r;
        const float* p = dB + sb + (size_t)pr * WDIM + (WDIM - 8 - c0);
        float4 a = *(const float4*)p;        // phys cols = logical c0+7..c0+4
        float4 b = *(const float4*)(p + 4);  // phys cols = logical c0+3..c0
        dst[7]=a.x; dst[6]=a.y; dst[5]=a.z; dst[4]=a.w;
        dst[3]=b.x; dst[2]=b.y; dst[1]=b.z; dst[0]=b.w;
    };

#pragma unroll
    for (int i = 0; i < 8; ++i) prev[i] = INF_W;
    float mx = 0.f;
#pragma unroll
    for (int k = 0; k < PF; ++k) load2(k, buf[k]);

    for (int rb = 0; rb < HDIM; rb += PF) {
#pragma unroll
        for (int k = 0; k < PF; ++k) {
            const int r = rb + k;
            row_step(jc, prev, buf[k]);
            if (r + PF < HDIM) load2(r + PF, buf[k]);
            float* sg = st[r & (SD - 1)];
#pragma unroll
            for (int i = 0; i < 8; ++i) { sg[i] = prev[i]; mx = fmaxf(mx, prev[i]); }
            int pr = HDIM - 1 - r;
            float* p = dA + sb + (size_t)pr * WDIM + (WDIM - 8 - c0);
            *(float4*)p       = make_float4(sg[7], sg[6], sg[5], sg[4]);
            *(float4*)(p + 4) = make_float4(sg[3], sg[2], sg[1], sg[0]);
        }
    }

#pragma unroll
    for (int off = 32; off > 0; off >>= 1) mx = fmaxf(mx, __shfl_xor(mx, off));
    if (lane == 0) acc[34 + s] = mx;
}

__global__ __launch_bounds__(256) void loss_kernel(const float* __restrict__ pred,
                                                   const int* __restrict__ tg,
                                                   const float* __restrict__ d,
                                                   const int* __restrict__ flags,
                                                   float* acc) {
    const int s = blockIdx.x >> 5;
    const int chunk = blockIdx.x & 31;
    const size_t base = (size_t)s * NPIX + (size_t)chunk * 8192;
    const float mxs = acc[34 + s];
    const bool hfg = flags[16 + s] != 0;
    const float scale = (mxs > 0.f) ? (1.f / fmaxf(mxs, 1e-12f)) : 1.f;
    const int tid = threadIdx.x;

    float facc = 0.f, bacc = 0.f, iacc = 0.f, pacc = 0.f;
    for (int it = 0; it < 8; ++it) {
        size_t idx = base + (size_t)(it * 256 + tid) * 4;
        float4 x4 = *(const float4*)(pred + idx);
        int4   t4 = *(const int4*)(tg + idx);
        float4 d4 = *(const float4*)(d + idx);
        float xs[4] = {x4.x, x4.y, x4.z, x4.w};
        int   ts[4] = {t4.x, t4.y, t4.z, t4.w};
        float dd[4] = {d4.x, d4.y, d4.z, d4.w};
#pragma unroll
        for (int i = 0; i < 4; ++i) {
            float x = xs[i];
            float e = __expf(-fabsf(x));       // exp(-|x|)
            float inv = 1.f / (1.f + e);
            float p = (x >= 0.f) ? inv : (1.f - inv);   // sigmoid(x)
            float L = __logf(1.f + e);                  // softplus(-|x|)
            bool t1 = ts[i] != 0;
            float fo = t1 ? 0.25f * (1.f - p) * (1.f - p) * (fmaxf(-x, 0.f) + L)
                          : 0.75f * p * p * (fmaxf(x, 0.f) + L);
            facc += fo;
            float dist = hfg ? dd[i] * scale : 1.f;
            bacc += (t1 ? (1.f - p) : p) * (1.f + dist);
            float tf = t1 ? 1.f : 0.f;
            iacc += tf * p;
            pacc += p + tf;
        }
    }
    __shared__ float red[4][4];
#pragma unroll
    for (int off = 32; off > 0; off >>= 1) {
        facc += __shfl_down(facc, off);
        bacc += __shfl_down(bacc, off);
        iacc += __shfl_down(iacc, off);
        pacc += __shfl_down(pacc, off);
    }
    int wave = tid >> 6;
    if ((tid & 63) == 0) { red[0][wave] = facc; red[1][wave] = bacc; red[2][wave] = iacc; red[3][wave] = pacc; }
    __syncthreads();
    if (tid == 0) {
        float f = 0, b = 0, i2 = 0, pp = 0;
        for (int w = 0; w < 4; ++w) { f += red[0][w]; b += red[1][w]; i2 += red[2][w]; pp += red[3][w]; }
        atomicAdd(&acc[0], f);
        atomicAdd(&acc[1], b);
        atomicAdd(&acc[2 + s], i2);
        atomicAdd(&acc[18 + s], pp);
    }
}

__global__ void final_kernel(const float* __restrict__ acc, const float* __restrict__ lv,
                             float* __restrict__ out) {
    if (threadIdx.x == 0) {
        float focal = acc[0] / NTOT_F;
        float bnd   = acc[1] / NTOT_F;
        float dsum = 0.f, isum = 0.f;
        for (int s = 0; s < NSAMP; ++s) {
            float inter = acc[2 + s];
            float tot   = acc[18 + s];
            dsum += (2.f * inter + 1e-6f) / (tot + 1e-6f);
            isum += (inter + 1e-6f) / (tot - inter + 1e-6f);
        }
        float dice = 1.f - dsum / 16.f;
        float iou  = 1.f - isum / 16.f;
        float l0 = lv[0], l1 = lv[1], l2 = lv[2], l3 = lv[3];
        float total = expf(-l0) * focal + l0 + expf(-l1) * dice + l1
                    + expf(-l2) * bnd  + l2 + expf(-l3) * iou  + l3;
        out[0] = total; out[1] = focal; out[2] = dice; out[3] = bnd; out[4] = iou;
    }
}

extern "C" void kernel_launch(void* const* d_in, const int* in_sizes, int n_in,
                              void* d_out, int out_size, void* d_ws, size_t ws_size,
                              hipStream_t stream) {
    const float* pred = (const float*)d_in[0];
    const int*   tg   = (const int*)d_in[1];
    const float* lv   = (const float*)d_in[2];
    float* out = (float*)d_out;
    char* ws = (char*)d_ws;
    float* acc      = (float*)ws;                 // 64 floats
    int*   flags    = (int*)(ws + 512);           // 64 ints
    int*   blkflags = (int*)(ws + 1024);          // 16384 ints
    float* dA       = (float*)(ws + 66560);       // 16 MB (seeds -> final DT)
    float* dB       = (float*)(ws + 66560 + (size_t)NSAMP * NPIX * 4);  // 16 MB

    hipMemsetAsync(ws, 0, 512, stream);
    seed_kernel<<<NSAMP * HDIM, 128, 0, stream>>>(tg, dA, blkflags);
    flagreduce_kernel<<<NSAMP, 64, 0, stream>>>(blkflags, flags);
    chamfer1_kernel<<<NSAMP, 64, 0, stream>>>(tg, dA, dB, flags);
    chamfer2_kernel<<<NSAMP, 64, 0, stream>>>(dB, dA, acc);
    loss_kernel<<<NSAMP * 32, 256, 0, stream>>>(pred, tg, dA, flags, acc);
    final_kernel<<<1, 64, 0, stream>>>(acc, lv, out);
}

// Round 7
// 338.108 us; speedup vs baseline: 4.0494x; 1.1595x over previous
//
#include <hip/hip_runtime.h>
#include <math.h>

#define A_W 0.955f
#define B_W 1.3693f
#define INF_W 1e6f
#define HDIM 512
#define WDIM 512
#define NPIX (HDIM*WDIM)
#define NSAMP 16
#define NTOT_F 4194304.0f
#define PF 8   // ring depth (loads + store staging share slots)

typedef float v4f __attribute__((ext_vector_type(4)));

// ws layout (bytes):
//  [0,256):      float acc[64]: [0]=focal_sum [1]=bnd_sum [2..17]=inter[s] [18..33]=totp[s] [34..49]=mx[s]
//  [512,768):    int flags[64]: [0..15]=has_b[s] [16..31]=has_fg[s]
//  [1024,66560): int blkflags[16384]
//  [66560, +16MB):  float dA[16][512][512]  (seeds -> final DT)
//  [+16MB, +32MB):  float dB[16][512][512]  (pass-1 intermediate)

template<int CTRL, int RMASK>
__device__ __forceinline__ float dpp_mov_inf(float x) {
    return __int_as_float(__builtin_amdgcn_update_dpp(
        __float_as_int(INF_W), __float_as_int(x), CTRL, RMASK, 0xF, false));
}

__device__ __forceinline__ float wave_prefix_min_incl(float t) {
    t = fminf(t, dpp_mov_inf<0x111,0xF>(t));   // row_shr:1
    t = fminf(t, dpp_mov_inf<0x112,0xF>(t));   // row_shr:2
    t = fminf(t, dpp_mov_inf<0x114,0xF>(t));   // row_shr:4
    t = fminf(t, dpp_mov_inf<0x118,0xF>(t));   // row_shr:8
    t = fminf(t, dpp_mov_inf<0x142,0xA>(t));   // row_bcast:15 -> rows 1,3
    t = fminf(t, dpp_mov_inf<0x143,0xC>(t));   // row_bcast:31 -> rows 2,3
    return t;
}

__device__ __forceinline__ void row_step(const float* jc, float* prev, const float* drow) {
    float lIn = dpp_mov_inf<0x138,0xF>(prev[7]);  // lane i <- lane i-1, lane0=INF
    float rIn = dpp_mov_inf<0x130,0xF>(prev[0]);  // lane i <- lane i+1, lane63=INF
    float g[8];
#pragma unroll
    for (int i = 0; i < 8; ++i) {
        float up = prev[i] + A_W;
        float ul = ((i == 0) ? lIn : prev[i-1]) + B_W;
        float ur = ((i == 7) ? rIn : prev[i+1]) + B_W;
        g[i] = fminf(fminf(drow[i], up), fminf(ul, ur)) - jc[i];
    }
    float c1[8];
    c1[0] = g[0];
#pragma unroll
    for (int i = 1; i < 8; ++i) c1[i] = fminf(g[i], g[i-1]);
    float c2[8];
    c2[0] = c1[0]; c2[1] = c1[1];
#pragma unroll
    for (int i = 2; i < 8; ++i) c2[i] = fminf(c1[i], c1[i-2]);
    float cj[8];
    cj[0] = c2[0]; cj[1] = c2[1]; cj[2] = c2[2]; cj[3] = c2[3];
#pragma unroll
    for (int i = 4; i < 8; ++i) cj[i] = fminf(c2[i], c2[i-4]);
    float t  = wave_prefix_min_incl(cj[7]);
    float ex = dpp_mov_inf<0x138,0xF>(t);
#pragma unroll
    for (int i = 0; i < 8; ++i) prev[i] = jc[i] + fminf(cj[i], ex);
}

// seed value: works for BOTH dA (0.0f / INF_W) and tg (0 / 1) inputs: bits==0 -> 0 else INF
__device__ __forceinline__ void cvt8(v4f a, v4f b, float* dr) {
#pragma unroll
    for (int i = 0; i < 4; ++i) dr[i]     = (__float_as_uint(a[i]) == 0u) ? 0.f : INF_W;
#pragma unroll
    for (int i = 0; i < 4; ++i) dr[4 + i] = (__float_as_uint(b[i]) == 0u) ? 0.f : INF_W;
}
__device__ __forceinline__ void rev8(v4f a, v4f b, float* dr) {
    dr[7]=a.x; dr[6]=a.y; dr[5]=a.z; dr[4]=a.w;
    dr[3]=b.x; dr[2]=b.y; dr[1]=b.z; dr[0]=b.w;
}
__device__ __forceinline__ v4f pack4(float a, float b, float c, float d) {
    v4f v; v.x=a; v.y=b; v.z=c; v.w=d; return v;
}

// ---- asm vmem ring machinery -------------------------------------------------
// Per step: 2 load ops + 2 store ops (all dwordx4) -> 4 vmcnt units.
// Steady state wait vmcnt(28) retires the load issued 8 steps ago AND the store
// issued 8 steps ago (so slot's data+addr regs are reusable). Ramp uses 14+2k.

#define RAMP_LOAD(K) \
  asm volatile("global_load_dwordx4 %0, %2, %3 offset:0\n\t" \
               "global_load_dwordx4 %1, %2, %3 offset:16" \
    : "=&v"(bA[K]), "=&v"(bB[K]) : "v"(vL[K]), "s"(srcb) : "memory")

#define CH_STEP1(K, VC) do { \
  asm volatile("s_waitcnt vmcnt(" #VC ")" \
    : "+v"(bA[K]), "+v"(bB[K]), "+v"(sA[K]), "+v"(sB[K]), "+v"(vL[K]), "+v"(vS[K]) \
    :: "memory"); \
  vL[K] += (r + PF < HDIM) ? 16384u : 0u; \
  vS[K] += 16384u; \
  float dr[8]; \
  cvt8(bA[K], bB[K], dr); \
  row_step(jc, prev, dr); \
  sA[K] = pack4(prev[0], prev[1], prev[2], prev[3]); \
  sB[K] = pack4(prev[4], prev[5], prev[6], prev[7]); \
  asm volatile("global_store_dwordx4 %0, %1, %3 offset:0\n\t" \
               "global_store_dwordx4 %0, %2, %3 offset:16" \
    :: "v"(vS[K]), "v"(sA[K]), "v"(sB[K]), "s"(dstb) : "memory"); \
  asm volatile("global_load_dwordx4 %0, %2, %3 offset:0\n\t" \
               "global_load_dwordx4 %1, %2, %3 offset:16" \
    : "=&v"(bA[K]), "=&v"(bB[K]) : "v"(vL[K]), "s"(srcb) : "memory"); \
  ++r; \
} while (0)

#define CH_STEP2(K, VC) do { \
  asm volatile("s_waitcnt vmcnt(" #VC ")" \
    : "+v"(bA[K]), "+v"(bB[K]), "+v"(sA[K]), "+v"(sB[K]), "+v"(vL[K]), "+v"(vS[K]) \
    :: "memory"); \
  vL[K] += (r + PF < HDIM) ? (unsigned)(-16384) : 0u; \
  vS[K] += (unsigned)(-16384); \
  float dr[8]; \
  rev8(bA[K], bB[K], dr); \
  row_step(jc, prev, dr); \
  _Pragma("unroll") \
  for (int i = 0; i < 8; ++i) mx = fmaxf(mx, prev[i]); \
  sA[K] = pack4(prev[7], prev[6], prev[5], prev[4]); \
  sB[K] = pack4(prev[3], prev[2], prev[1], prev[0]); \
  asm volatile("global_store_dwordx4 %0, %1, %3 offset:0\n\t" \
               "global_store_dwordx4 %0, %2, %3 offset:16" \
    :: "v"(vS[K]), "v"(sA[K]), "v"(sB[K]), "s"(dstb) : "memory"); \
  asm volatile("global_load_dwordx4 %0, %2, %3 offset:0\n\t" \
               "global_load_dwordx4 %1, %2, %3 offset:16" \
    : "=&v"(bA[K]), "=&v"(bB[K]) : "v"(vL[K]), "s"(srcb) : "memory"); \
  ++r; \
} while (0)

__global__ __launch_bounds__(128) void seed_kernel(const int* __restrict__ tg,
                                                   float* __restrict__ d,
                                                   int* __restrict__ blkflags) {
    const int s = blockIdx.x >> 9;
    const int r = blockIdx.x & 511;
    const int tid = threadIdx.x;
    const int c0 = tid * 4;
    const size_t sb = (size_t)s * NPIX;

    bool fg[6], bg[6];
#pragma unroll
    for (int j = 0; j < 6; ++j) { fg[j] = false; bg[j] = false; }
    int4 center = make_int4(0, 0, 0, 0);
#pragma unroll
    for (int dr = -1; dr <= 1; ++dr) {
        int rr = r + dr;
        if (rr < 0 || rr >= HDIM) continue;
        const int* rowp = tg + sb + (size_t)rr * WDIM;
        int4 cc = *(const int4*)(rowp + c0);
        if (dr == 0) center = cc;
        int vl = (c0 > 0) ? rowp[c0 - 1] : -1;
        int vr = (c0 + 4 < WDIM) ? rowp[c0 + 4] : -1;
        int v[6] = {vl, cc.x, cc.y, cc.z, cc.w, vr};
#pragma unroll
        for (int j = 0; j < 6; ++j) {
            if (v[j] >= 0) { fg[j] = fg[j] || (v[j] != 0); bg[j] = bg[j] || (v[j] == 0); }
        }
    }
    float out[4];
    bool anyb = false;
#pragma unroll
    for (int i = 0; i < 4; ++i) {
        bool f = fg[i] || fg[i + 1] || fg[i + 2];
        bool b = bg[i] || bg[i + 1] || bg[i + 2];
        bool bd = f && b;
        anyb = anyb || bd;
        out[i] = bd ? 0.0f : INF_W;
    }
    bool anyfg = (center.x | center.y | center.z | center.w) != 0;
    *(float4*)(d + sb + (size_t)r * WDIM + c0) = make_float4(out[0], out[1], out[2], out[3]);

    int wb = __any((int)anyb)  ? 1 : 0;
    int wf = __any((int)anyfg) ? 2 : 0;
    if ((tid & 63) == 0) blkflags[blockIdx.x * 2 + (tid >> 6)] = wb | wf;
}

__global__ __launch_bounds__(64) void flagreduce_kernel(const int* __restrict__ blkflags,
                                                        int* __restrict__ flags) {
    const int s = blockIdx.x;
    const int lane = threadIdx.x;
    const int4* p = (const int4*)(blkflags + s * 1024);
    int v = 0;
#pragma unroll
    for (int i = 0; i < 4; ++i) {
        int4 e = p[lane + 64 * i];
        v |= e.x | e.y | e.z | e.w;
    }
#pragma unroll
    for (int off = 32; off > 0; off >>= 1) v |= __shfl_xor(v, off);
    if (lane == 0) { flags[s] = v & 1; flags[16 + s] = (v >> 1) & 1; }
}

// PASS 1 (top-down): src = dA seeds (or tg directly), dst = dB.
__global__ __launch_bounds__(64) void chamfer1_kernel(const int* __restrict__ tg,
                                                      const float* __restrict__ dA,
                                                      float* __restrict__ dB,
                                                      const int* __restrict__ flags) {
    const int s = blockIdx.x;
    const int lane = threadIdx.x;
    const size_t sb = (size_t)s * NPIX;
    const bool useb = flags[s] != 0;
    const int c0 = lane * 8;

    const void* srcb = useb ? (const void*)(dA + sb) : (const void*)(tg + sb);
    void* dstb = (void*)(dB + sb);

    float jc[8];
#pragma unroll
    for (int i = 0; i < 8; ++i) jc[i] = A_W * (float)(c0 + i);

    v4f bA[PF], bB[PF], sA[PF], sB[PF];
    unsigned vL[PF], vS[PF];
    const unsigned laneoff = (unsigned)lane * 32u;
#pragma unroll
    for (int k = 0; k < PF; ++k) {
        vL[k] = (unsigned)k * 2048u + laneoff;
        vS[k] = (unsigned)k * 2048u + laneoff - 16384u;  // +16384 at first use -> row k
        sA[k] = pack4(0.f, 0.f, 0.f, 0.f);
        sB[k] = pack4(0.f, 0.f, 0.f, 0.f);
    }
    RAMP_LOAD(0); RAMP_LOAD(1); RAMP_LOAD(2); RAMP_LOAD(3);
    RAMP_LOAD(4); RAMP_LOAD(5); RAMP_LOAD(6); RAMP_LOAD(7);

    float prev[8];
#pragma unroll
    for (int i = 0; i < 8; ++i) prev[i] = INF_W;

    int r = 0;
    CH_STEP1(0,14); CH_STEP1(1,16); CH_STEP1(2,18); CH_STEP1(3,20);
    CH_STEP1(4,22); CH_STEP1(5,24); CH_STEP1(6,26); CH_STEP1(7,28);
    for (int rb = 8; rb < HDIM; rb += 8) {
        CH_STEP1(0,28); CH_STEP1(1,28); CH_STEP1(2,28); CH_STEP1(3,28);
        CH_STEP1(4,28); CH_STEP1(5,28); CH_STEP1(6,28); CH_STEP1(7,28);
    }
    asm volatile("s_waitcnt vmcnt(0)" ::: "memory");
}

// PASS 2 (bottom-up, flipped): src = dB, dst = dA; tracks per-sample max.
__global__ __launch_bounds__(64) void chamfer2_kernel(const float* __restrict__ dB,
                                                      float* __restrict__ dA,
                                                      float* __restrict__ acc) {
    const int s = blockIdx.x;
    const int lane = threadIdx.x;
    const size_t sb = (size_t)s * NPIX;
    const int c0 = lane * 8;

    const void* srcb = (const void*)(dB + sb);
    void* dstb = (void*)(dA + sb);

    float jc[8];
#pragma unroll
    for (int i = 0; i < 8; ++i) jc[i] = A_W * (float)(c0 + i);

    v4f bA[PF], bB[PF], sA[PF], sB[PF];
    unsigned vL[PF], vS[PF];
    const unsigned laneoff = 2016u - (unsigned)lane * 32u;
#pragma unroll
    for (int k = 0; k < PF; ++k) {
        vL[k] = (unsigned)(511 - k) * 2048u + laneoff;
        vS[k] = vL[k] + 16384u;                          // -16384 at first use -> row 511-k
        sA[k] = pack4(0.f, 0.f, 0.f, 0.f);
        sB[k] = pack4(0.f, 0.f, 0.f, 0.f);
    }
    RAMP_LOAD(0); RAMP_LOAD(1); RAMP_LOAD(2); RAMP_LOAD(3);
    RAMP_LOAD(4); RAMP_LOAD(5); RAMP_LOAD(6); RAMP_LOAD(7);

    float prev[8];
#pragma unroll
    for (int i = 0; i < 8; ++i) prev[i] = INF_W;
    float mx = 0.f;

    int r = 0;
    CH_STEP2(0,14); CH_STEP2(1,16); CH_STEP2(2,18); CH_STEP2(3,20);
    CH_STEP2(4,22); CH_STEP2(5,24); CH_STEP2(6,26); CH_STEP2(7,28);
    for (int rb = 8; rb < HDIM; rb += 8) {
        CH_STEP2(0,28); CH_STEP2(1,28); CH_STEP2(2,28); CH_STEP2(3,28);
        CH_STEP2(4,28); CH_STEP2(5,28); CH_STEP2(6,28); CH_STEP2(7,28);
    }
    asm volatile("s_waitcnt vmcnt(0)" ::: "memory");

#pragma unroll
    for (int off = 32; off > 0; off >>= 1) mx = fmaxf(mx, __shfl_xor(mx, off));
    if (lane == 0) acc[34 + s] = mx;
}

__global__ __launch_bounds__(256) void loss_kernel(const float* __restrict__ pred,
                                                   const int* __restrict__ tg,
                                                   const float* __restrict__ d,
                                                   const int* __restrict__ flags,
                                                   float* acc) {
    const int s = blockIdx.x >> 5;
    const int chunk = blockIdx.x & 31;
    const size_t base = (size_t)s * NPIX + (size_t)chunk * 8192;
    const float mxs = acc[34 + s];
    const bool hfg = flags[16 + s] != 0;
    const float scale = (mxs > 0.f) ? (1.f / fmaxf(mxs, 1e-12f)) : 1.f;
    const int tid = threadIdx.x;

    float facc = 0.f, bacc = 0.f, iacc = 0.f, pacc = 0.f;
    for (int it = 0; it < 8; ++it) {
        size_t idx = base + (size_t)(it * 256 + tid) * 4;
        float4 x4 = *(const float4*)(pred + idx);
        int4   t4 = *(const int4*)(tg + idx);
        float4 d4 = *(const float4*)(d + idx);
        float xs[4] = {x4.x, x4.y, x4.z, x4.w};
        int   ts[4] = {t4.x, t4.y, t4.z, t4.w};
        float dd[4] = {d4.x, d4.y, d4.z, d4.w};
#pragma unroll
        for (int i = 0; i < 4; ++i) {
            float x = xs[i];
            float e = __expf(-fabsf(x));
            float inv = 1.f / (1.f + e);
            float p = (x >= 0.f) ? inv : (1.f - inv);
            float L = __logf(1.f + e);
            bool t1 = ts[i] != 0;
            float fo = t1 ? 0.25f * (1.f - p) * (1.f - p) * (fmaxf(-x, 0.f) + L)
                          : 0.75f * p * p * (fmaxf(x, 0.f) + L);
            facc += fo;
            float dist = hfg ? dd[i] * scale : 1.f;
            bacc += (t1 ? (1.f - p) : p) * (1.f + dist);
            float tf = t1 ? 1.f : 0.f;
            iacc += tf * p;
            pacc += p + tf;
        }
    }
    __shared__ float red[4][4];
#pragma unroll
    for (int off = 32; off > 0; off >>= 1) {
        facc += __shfl_down(facc, off);
        bacc += __shfl_down(bacc, off);
        iacc += __shfl_down(iacc, off);
        pacc += __shfl_down(pacc, off);
    }
    int wave = tid >> 6;
    if ((tid & 63) == 0) { red[0][wave] = facc; red[1][wave] = bacc; red[2][wave] = iacc; red[3][wave] = pacc; }
    __syncthreads();
    if (tid == 0) {
        float f = 0, b = 0, i2 = 0, pp = 0;
        for (int w = 0; w < 4; ++w) { f += red[0][w]; b += red[1][w]; i2 += red[2][w]; pp += red[3][w]; }
        atomicAdd(&acc[0], f);
        atomicAdd(&acc[1], b);
        atomicAdd(&acc[2 + s], i2);
        atomicAdd(&acc[18 + s], pp);
    }
}

__global__ void final_kernel(const float* __restrict__ acc, const float* __restrict__ lv,
                             float* __restrict__ out) {
    if (threadIdx.x == 0) {
        float focal = acc[0] / NTOT_F;
        float bnd   = acc[1] / NTOT_F;
        float dsum = 0.f, isum = 0.f;
        for (int s = 0; s < NSAMP; ++s) {
            float inter = acc[2 + s];
            float tot   = acc[18 + s];
            dsum += (2.f * inter + 1e-6f) / (tot + 1e-6f);
            isum += (inter + 1e-6f) / (tot - inter + 1e-6f);
        }
        float dice = 1.f - dsum / 16.f;
        float iou  = 1.f - isum / 16.f;
        float l0 = lv[0], l1 = lv[1], l2 = lv[2], l3 = lv[3];
        float total = expf(-l0) * focal + l0 + expf(-l1) * dice + l1
                    + expf(-l2) * bnd  + l2 + expf(-l3) * iou  + l3;
        out[0] = total; out[1] = focal; out[2] = dice; out[3] = bnd; out[4] = iou;
    }
}

extern "C" void kernel_launch(void* const* d_in, const int* in_sizes, int n_in,
                              void* d_out, int out_size, void* d_ws, size_t ws_size,
                              hipStream_t stream) {
    const float* pred = (const float*)d_in[0];
    const int*   tg   = (const int*)d_in[1];
    const float* lv   = (const float*)d_in[2];
    float* out = (float*)d_out;
    char* ws = (char*)d_ws;
    float* acc      = (float*)ws;                 // 64 floats
    int*   flags    = (int*)(ws + 512);           // 64 ints
    int*   blkflags = (int*)(ws + 1024);          // 16384 ints
    float* dA       = (float*)(ws + 66560);       // 16 MB (seeds -> final DT)
    float* dB       = (float*)(ws + 66560 + (size_t)NSAMP * NPIX * 4);  // 16 MB

    hipMemsetAsync(ws, 0, 512, stream);
    seed_kernel<<<NSAMP * HDIM, 128, 0, stream>>>(tg, dA, blkflags);
    flagreduce_kernel<<<NSAMP, 64, 0, stream>>>(blkflags, flags);
    chamfer1_kernel<<<NSAMP, 64, 0, stream>>>(tg, dA, dB, flags);
    chamfer2_kernel<<<NSAMP, 64, 0, stream>>>(dB, dA, acc);
    loss_kernel<<<NSAMP * 32, 256, 0, stream>>>(pred, tg, dA, flags, acc);
    final_kernel<<<1, 64, 0, stream>>>(acc, lv, out);
}

// Round 8
// 214.642 us; speedup vs baseline: 6.3786x; 1.5752x over previous
//
#include <hip/hip_runtime.h>
#include <math.h>

#define A_W 0.955f
#define B_W 1.3693f
#define INF_W 1e6f
#define HDIM 512
#define WDIM 512
#define NPIX (HDIM*WDIM)
#define NSAMP 16
#define NTOT_F 4194304.0f
#define TST 16      // strip height
#define NSTRIP 32   // strips per sample

// ws layout (bytes):
//  [0,256):        float acc[64]: [0]=focal [1]=bnd [2..17]=inter [18..33]=totp [34..49]=mx
//  [512,768):      int flags[64]: [0..15]=has_b [16..31]=has_fg
//  [1024,66560):   int blkflags[16384]
//  [66560,68608):  float stripmax[512]
//  [1MB,2MB):      float Llast[16][32][512]   (reused by both passes)
//  [2MB,3MB):      float bounds[16][32][512]  (reused by both passes)
//  [3MB,19MB):     float dA[16][512][512]     (seeds -> final DT)
//  [19MB,35MB):    float dB[16][512][512]     (pass-1 result)
#define OFF_SMAX   66560
#define OFF_LLAST  (1u<<20)
#define OFF_BOUNDS (2u<<20)
#define OFF_DA     (3u<<20)
#define OFF_DB     (OFF_DA + (unsigned)NSAMP*NPIX*4u)

// DPP move with INF fill.
//   WAVE_SHR1 (0x138): lane i <- lane i-1 (== __shfl_up 1)
//   WAVE_SHL1 (0x130): lane i <- lane i+1 (== __shfl_down 1)
template<int CTRL, int RMASK>
__device__ __forceinline__ float dpp_mov_inf(float x) {
    return __int_as_float(__builtin_amdgcn_update_dpp(
        __float_as_int(INF_W), __float_as_int(x), CTRL, RMASK, 0xF, false));
}

__device__ __forceinline__ float wave_prefix_min_incl(float t) {
    t = fminf(t, dpp_mov_inf<0x111,0xF>(t));   // row_shr:1
    t = fminf(t, dpp_mov_inf<0x112,0xF>(t));   // row_shr:2
    t = fminf(t, dpp_mov_inf<0x114,0xF>(t));   // row_shr:4
    t = fminf(t, dpp_mov_inf<0x118,0xF>(t));   // row_shr:8
    t = fminf(t, dpp_mov_inf<0x142,0xA>(t));   // row_bcast:15 -> rows 1,3
    t = fminf(t, dpp_mov_inf<0x143,0xC>(t));   // row_bcast:31 -> rows 2,3
    return t;
}

// v[j] <- min_{k<=j} (v[k] + A*(j-k))   (wave-wide, 8 cols/lane)
__device__ __forceinline__ void cummin_row(const float* jc, float* v) {
    float g[8];
#pragma unroll
    for (int i = 0; i < 8; ++i) g[i] = v[i] - jc[i];
    float c1[8];
    c1[0] = g[0];
#pragma unroll
    for (int i = 1; i < 8; ++i) c1[i] = fminf(g[i], g[i-1]);
    float c2[8];
    c2[0] = c1[0]; c2[1] = c1[1];
#pragma unroll
    for (int i = 2; i < 8; ++i) c2[i] = fminf(c1[i], c1[i-2]);
    float cj[8];
    cj[0] = c2[0]; cj[1] = c2[1]; cj[2] = c2[2]; cj[3] = c2[3];
#pragma unroll
    for (int i = 4; i < 8; ++i) cj[i] = fminf(c2[i], c2[i-4]);
    float t  = wave_prefix_min_incl(cj[7]);
    float ex = dpp_mov_inf<0x138,0xF>(t);
#pragma unroll
    for (int i = 0; i < 8; ++i) v[i] = jc[i] + fminf(cj[i], ex);
}

// One full chamfer row-step (vertical 3-tap + rightward cummin).
__device__ __forceinline__ void row_step(const float* jc, float* prev, const float* drow) {
    float lIn = dpp_mov_inf<0x138,0xF>(prev[7]);
    float rIn = dpp_mov_inf<0x130,0xF>(prev[0]);
    float m[8];
#pragma unroll
    for (int i = 0; i < 8; ++i) {
        float up = prev[i] + A_W;
        float ul = ((i == 0) ? lIn : prev[i-1]) + B_W;
        float ur = ((i == 7) ? rIn : prev[i+1]) + B_W;
        m[i] = fminf(fminf(drow[i], up), fminf(ul, ur));
    }
    cummin_row(jc, m);
#pragma unroll
    for (int i = 0; i < 8; ++i) prev[i] = m[i];
}

// 4 fused T3 steps: b <- min_{|d|<=4} (b[j-d] + B|d| + A(4-|d|)); out-of-grid = INF.
__device__ __forceinline__ void t3x4(float* b) {
    float e[16];
#pragma unroll
    for (int k = 0; k < 4; ++k) e[k]    = dpp_mov_inf<0x138,0xF>(b[4+k]); // cols c0-4..c0-1
#pragma unroll
    for (int k = 0; k < 8; ++k) e[4+k]  = b[k];
#pragma unroll
    for (int k = 0; k < 4; ++k) e[12+k] = dpp_mov_inf<0x130,0xF>(b[k]);  // cols c0+8..c0+11
    const float w0 = 4.f*A_W, w1 = 3.f*A_W + B_W, w2 = 2.f*A_W + 2.f*B_W;
    const float w3 = A_W + 3.f*B_W, w4 = 4.f*B_W;
#pragma unroll
    for (int i = 0; i < 8; ++i) {
        float m = e[i+4] + w0;
        m = fminf(m, fminf(e[i+3], e[i+5]) + w1);
        m = fminf(m, fminf(e[i+2], e[i+6]) + w2);
        m = fminf(m, fminf(e[i+1], e[i+7]) + w3);
        m = fminf(m, fminf(e[i+0], e[i+8]) + w4);
        b[i] = m;
    }
}

__global__ __launch_bounds__(128) void seed_kernel(const int* __restrict__ tg,
                                                   float* __restrict__ d,
                                                   int* __restrict__ blkflags) {
    const int s = blockIdx.x >> 9;
    const int r = blockIdx.x & 511;
    const int tid = threadIdx.x;
    const int c0 = tid * 4;
    const size_t sb = (size_t)s * NPIX;

    bool fg[6], bg[6];
#pragma unroll
    for (int j = 0; j < 6; ++j) { fg[j] = false; bg[j] = false; }
    int4 center = make_int4(0, 0, 0, 0);
#pragma unroll
    for (int dr = -1; dr <= 1; ++dr) {
        int rr = r + dr;
        if (rr < 0 || rr >= HDIM) continue;
        const int* rowp = tg + sb + (size_t)rr * WDIM;
        int4 cc = *(const int4*)(rowp + c0);
        if (dr == 0) center = cc;
        int vl = (c0 > 0) ? rowp[c0 - 1] : -1;
        int vr = (c0 + 4 < WDIM) ? rowp[c0 + 4] : -1;
        int v[6] = {vl, cc.x, cc.y, cc.z, cc.w, vr};
#pragma unroll
        for (int j = 0; j < 6; ++j) {
            if (v[j] >= 0) { fg[j] = fg[j] || (v[j] != 0); bg[j] = bg[j] || (v[j] == 0); }
        }
    }
    float out[4];
    bool anyb = false;
#pragma unroll
    for (int i = 0; i < 4; ++i) {
        bool f = fg[i] || fg[i + 1] || fg[i + 2];
        bool b = bg[i] || bg[i + 1] || bg[i + 2];
        bool bd = f && b;
        anyb = anyb || bd;
        out[i] = bd ? 0.0f : INF_W;
    }
    bool anyfg = (center.x | center.y | center.z | center.w) != 0;
    *(float4*)(d + sb + (size_t)r * WDIM + c0) = make_float4(out[0], out[1], out[2], out[3]);

    int wb = __any((int)anyb)  ? 1 : 0;
    int wf = __any((int)anyfg) ? 2 : 0;
    if ((tid & 63) == 0) blkflags[blockIdx.x * 2 + (tid >> 6)] = wb | wf;
}

__global__ __launch_bounds__(64) void flagreduce_kernel(const int* __restrict__ blkflags,
                                                        int* __restrict__ flags) {
    const int s = blockIdx.x;
    const int lane = threadIdx.x;
    const int4* p = (const int4*)(blkflags + s * 1024);
    int v = 0;
#pragma unroll
    for (int i = 0; i < 4; ++i) {
        int4 e = p[lane + 64 * i];
        v |= e.x | e.y | e.z | e.w;
    }
#pragma unroll
    for (int off = 32; off > 0; off >>= 1) v |= __shfl_xor(v, off);
    if (lane == 0) { flags[s] = v & 1; flags[16 + s] = (v >> 1) & 1; }
}

// Phase 1, pass 1: per strip, local result with INF incoming; write last row only.
__global__ __launch_bounds__(64) void strip1a_kernel(const int* __restrict__ tg,
                                                     const float* __restrict__ dA,
                                                     const int* __restrict__ flags,
                                                     float* __restrict__ Llast) {
    const int s = blockIdx.x >> 5, sig = blockIdx.x & 31;
    const int lane = threadIdx.x;
    const int c0 = lane * 8;
    const size_t sb = (size_t)s * NPIX;
    const bool useb = flags[s] != 0;
    const unsigned int* src = (useb ? (const unsigned int*)dA : (const unsigned int*)tg)
                              + sb + (size_t)(sig * TST) * WDIM;
    float jc[8];
#pragma unroll
    for (int i = 0; i < 8; ++i) jc[i] = A_W * (float)(c0 + i);
    float prev[8];
#pragma unroll
    for (int i = 0; i < 8; ++i) prev[i] = INF_W;

#pragma unroll
    for (int t = 0; t < TST; ++t) {
        uint4 a = *(const uint4*)(src + (size_t)t * WDIM + c0);
        uint4 b = *(const uint4*)(src + (size_t)t * WDIM + c0 + 4);
        float dr[8];
        dr[0]=(a.x==0u)?0.f:INF_W; dr[1]=(a.y==0u)?0.f:INF_W; dr[2]=(a.z==0u)?0.f:INF_W; dr[3]=(a.w==0u)?0.f:INF_W;
        dr[4]=(b.x==0u)?0.f:INF_W; dr[5]=(b.y==0u)?0.f:INF_W; dr[6]=(b.z==0u)?0.f:INF_W; dr[7]=(b.w==0u)?0.f:INF_W;
        row_step(jc, prev, dr);
    }
    float* Lr = Llast + ((size_t)s * NSTRIP + sig) * WDIM + c0;
    *(float4*)Lr       = make_float4(prev[0], prev[1], prev[2], prev[3]);
    *(float4*)(Lr + 4) = make_float4(prev[4], prev[5], prev[6], prev[7]);
}

// Phase 2 (both passes): exact sequential boundary propagation across strips.
__global__ __launch_bounds__(64) void bounds_kernel(const float* __restrict__ Llast,
                                                    float* __restrict__ bounds) {
    const int s = blockIdx.x;
    const int lane = threadIdx.x;
    const int c0 = lane * 8;
    float jc[8];
#pragma unroll
    for (int i = 0; i < 8; ++i) jc[i] = A_W * (float)(c0 + i);
    const float* Lb = Llast + (size_t)s * NSTRIP * WDIM;
    float* Bb = bounds + (size_t)s * NSTRIP * WDIM;

    float b[8];
    {
        float4 l0 = *(const float4*)(Lb + c0);
        float4 l1 = *(const float4*)(Lb + c0 + 4);
        b[0]=l0.x; b[1]=l0.y; b[2]=l0.z; b[3]=l0.w;
        b[4]=l1.x; b[5]=l1.y; b[6]=l1.z; b[7]=l1.w;
        *(float4*)(Bb + c0)     = l0;
        *(float4*)(Bb + c0 + 4) = l1;
    }
    for (int sig = 1; sig < NSTRIP; ++sig) {
        const float* Lr = Lb + (size_t)sig * WDIM + c0;
        float4 l0 = *(const float4*)Lr;          // prefetch before the serial chain
        float4 l1 = *(const float4*)(Lr + 4);
        t3x4(b); t3x4(b); t3x4(b); t3x4(b);      // T3^16 exact (TST==16)
        cummin_row(jc, b);
        b[0]=fminf(b[0],l0.x); b[1]=fminf(b[1],l0.y); b[2]=fminf(b[2],l0.z); b[3]=fminf(b[3],l0.w);
        b[4]=fminf(b[4],l1.x); b[5]=fminf(b[5],l1.y); b[6]=fminf(b[6],l1.z); b[7]=fminf(b[7],l1.w);
        float* Br = Bb + (size_t)sig * WDIM + c0;
        *(float4*)Br       = make_float4(b[0], b[1], b[2], b[3]);
        *(float4*)(Br + 4) = make_float4(b[4], b[5], b[6], b[7]);
    }
}

// Phase 3, pass 1: per strip, exact rows from exact incoming boundary; write all rows to dB.
__global__ __launch_bounds__(64) void strip3a_kernel(const int* __restrict__ tg,
                                                     const float* __restrict__ dA,
                                                     const int* __restrict__ flags,
                                                     const float* __restrict__ bounds,
                                                     float* __restrict__ dB) {
    const int s = blockIdx.x >> 5, sig = blockIdx.x & 31;
    const int lane = threadIdx.x;
    const int c0 = lane * 8;
    const size_t sb = (size_t)s * NPIX;
    const bool useb = flags[s] != 0;
    const unsigned int* src = (useb ? (const unsigned int*)dA : (const unsigned int*)tg)
                              + sb + (size_t)(sig * TST) * WDIM;
    float jc[8];
#pragma unroll
    for (int i = 0; i < 8; ++i) jc[i] = A_W * (float)(c0 + i);
    float prev[8];
    if (sig == 0) {
#pragma unroll
        for (int i = 0; i < 8; ++i) prev[i] = INF_W;
    } else {
        const float* Br = bounds + ((size_t)s * NSTRIP + (sig - 1)) * WDIM + c0;
        float4 b0 = *(const float4*)Br;
        float4 b1 = *(const float4*)(Br + 4);
        prev[0]=b0.x; prev[1]=b0.y; prev[2]=b0.z; prev[3]=b0.w;
        prev[4]=b1.x; prev[5]=b1.y; prev[6]=b1.z; prev[7]=b1.w;
    }
    float* dst = dB + sb + (size_t)(sig * TST) * WDIM;
#pragma unroll
    for (int t = 0; t < TST; ++t) {
        uint4 a = *(const uint4*)(src + (size_t)t * WDIM + c0);
        uint4 b = *(const uint4*)(src + (size_t)t * WDIM + c0 + 4);
        float dr[8];
        dr[0]=(a.x==0u)?0.f:INF_W; dr[1]=(a.y==0u)?0.f:INF_W; dr[2]=(a.z==0u)?0.f:INF_W; dr[3]=(a.w==0u)?0.f:INF_W;
        dr[4]=(b.x==0u)?0.f:INF_W; dr[5]=(b.y==0u)?0.f:INF_W; dr[6]=(b.z==0u)?0.f:INF_W; dr[7]=(b.w==0u)?0.f:INF_W;
        row_step(jc, prev, dr);
        float* p = dst + (size_t)t * WDIM + c0;
        *(float4*)p       = make_float4(prev[0], prev[1], prev[2], prev[3]);
        *(float4*)(p + 4) = make_float4(prev[4], prev[5], prev[6], prev[7]);
    }
}

// Phase 1, pass 2 (flipped): local strip result from dB; write last (logical) row.
__global__ __launch_bounds__(64) void strip1b_kernel(const float* __restrict__ dB,
                                                     float* __restrict__ Llast) {
    const int s = blockIdx.x >> 5, sig = blockIdx.x & 31;
    const int lane = threadIdx.x;
    const int c0 = lane * 8;
    const size_t sb = (size_t)s * NPIX;
    float jc[8];
#pragma unroll
    for (int i = 0; i < 8; ++i) jc[i] = A_W * (float)(c0 + i);
    float prev[8];
#pragma unroll
    for (int i = 0; i < 8; ++i) prev[i] = INF_W;

#pragma unroll
    for (int t = 0; t < TST; ++t) {
        int pr = HDIM - 1 - (sig * TST + t);
        const float* p = dB + sb + (size_t)pr * WDIM + (WDIM - 8 - c0);
        float4 a = *(const float4*)p;        // phys cols -> logical c0+7..c0+4
        float4 b = *(const float4*)(p + 4);  // -> logical c0+3..c0
        float dr[8];
        dr[7]=a.x; dr[6]=a.y; dr[5]=a.z; dr[4]=a.w;
        dr[3]=b.x; dr[2]=b.y; dr[1]=b.z; dr[0]=b.w;
        row_step(jc, prev, dr);
    }
    float* Lr = Llast + ((size_t)s * NSTRIP + sig) * WDIM + c0;
    *(float4*)Lr       = make_float4(prev[0], prev[1], prev[2], prev[3]);
    *(float4*)(Lr + 4) = make_float4(prev[4], prev[5], prev[6], prev[7]);
}

// Phase 3, pass 2 (flipped): exact rows -> dA (physical layout), per-strip max.
__global__ __launch_bounds__(64) void strip3b_kernel(const float* __restrict__ dB,
                                                     const float* __restrict__ bounds,
                                                     float* __restrict__ dA,
                                                     float* __restrict__ stripmax) {
    const int s = blockIdx.x >> 5, sig = blockIdx.x & 31;
    const int lane = threadIdx.x;
    const int c0 = lane * 8;
    const size_t sb = (size_t)s * NPIX;
    float jc[8];
#pragma unroll
    for (int i = 0; i < 8; ++i) jc[i] = A_W * (float)(c0 + i);
    float prev[8];
    if (sig == 0) {
#pragma unroll
        for (int i = 0; i < 8; ++i) prev[i] = INF_W;
    } else {
        const float* Br = bounds + ((size_t)s * NSTRIP + (sig - 1)) * WDIM + c0;
        float4 b0 = *(const float4*)Br;
        float4 b1 = *(const float4*)(Br + 4);
        prev[0]=b0.x; prev[1]=b0.y; prev[2]=b0.z; prev[3]=b0.w;
        prev[4]=b1.x; prev[5]=b1.y; prev[6]=b1.z; prev[7]=b1.w;
    }
    float mx = 0.f;
#pragma unroll
    for (int t = 0; t < TST; ++t) {
        int pr = HDIM - 1 - (sig * TST + t);
        const float* p = dB + sb + (size_t)pr * WDIM + (WDIM - 8 - c0);
        float4 a = *(const float4*)p;
        float4 b = *(const float4*)(p + 4);
        float dr[8];
        dr[7]=a.x; dr[6]=a.y; dr[5]=a.z; dr[4]=a.w;
        dr[3]=b.x; dr[2]=b.y; dr[1]=b.z; dr[0]=b.w;
        row_step(jc, prev, dr);
#pragma unroll
        for (int i = 0; i < 8; ++i) mx = fmaxf(mx, prev[i]);
        float* q = dA + sb + (size_t)pr * WDIM + (WDIM - 8 - c0);
        *(float4*)q       = make_float4(prev[7], prev[6], prev[5], prev[4]);
        *(float4*)(q + 4) = make_float4(prev[3], prev[2], prev[1], prev[0]);
    }
#pragma unroll
    for (int off = 32; off > 0; off >>= 1) mx = fmaxf(mx, __shfl_xor(mx, off));
    if (lane == 0) stripmax[s * NSTRIP + sig] = mx;
}

__global__ __launch_bounds__(64) void maxred_kernel(const float* __restrict__ stripmax,
                                                    float* __restrict__ acc) {
    const int s = blockIdx.x;
    const int lane = threadIdx.x;
    float v = (lane < NSTRIP) ? stripmax[s * NSTRIP + lane] : 0.f;
#pragma unroll
    for (int off = 32; off > 0; off >>= 1) v = fmaxf(v, __shfl_xor(v, off));
    if (lane == 0) acc[34 + s] = v;
}

__global__ __launch_bounds__(256) void loss_kernel(const float* __restrict__ pred,
                                                   const int* __restrict__ tg,
                                                   const float* __restrict__ d,
                                                   const int* __restrict__ flags,
                                                   float* acc) {
    const int s = blockIdx.x >> 5;
    const int chunk = blockIdx.x & 31;
    const size_t base = (size_t)s * NPIX + (size_t)chunk * 8192;
    const float mxs = acc[34 + s];
    const bool hfg = flags[16 + s] != 0;
    const float scale = (mxs > 0.f) ? (1.f / fmaxf(mxs, 1e-12f)) : 1.f;
    const int tid = threadIdx.x;

    float facc = 0.f, bacc = 0.f, iacc = 0.f, pacc = 0.f;
    for (int it = 0; it < 8; ++it) {
        size_t idx = base + (size_t)(it * 256 + tid) * 4;
        float4 x4 = *(const float4*)(pred + idx);
        int4   t4 = *(const int4*)(tg + idx);
        float4 d4 = *(const float4*)(d + idx);
        float xs[4] = {x4.x, x4.y, x4.z, x4.w};
        int   ts[4] = {t4.x, t4.y, t4.z, t4.w};
        float dd[4] = {d4.x, d4.y, d4.z, d4.w};
#pragma unroll
        for (int i = 0; i < 4; ++i) {
            float x = xs[i];
            float e = __expf(-fabsf(x));
            float inv = 1.f / (1.f + e);
            float p = (x >= 0.f) ? inv : (1.f - inv);
            float L = __logf(1.f + e);
            bool t1 = ts[i] != 0;
            float fo = t1 ? 0.25f * (1.f - p) * (1.f - p) * (fmaxf(-x, 0.f) + L)
                          : 0.75f * p * p * (fmaxf(x, 0.f) + L);
            facc += fo;
            float dist = hfg ? dd[i] * scale : 1.f;
            bacc += (t1 ? (1.f - p) : p) * (1.f + dist);
            float tf = t1 ? 1.f : 0.f;
            iacc += tf * p;
            pacc += p + tf;
        }
    }
    __shared__ float red[4][4];
#pragma unroll
    for (int off = 32; off > 0; off >>= 1) {
        facc += __shfl_down(facc, off);
        bacc += __shfl_down(bacc, off);
        iacc += __shfl_down(iacc, off);
        pacc += __shfl_down(pacc, off);
    }
    int wave = tid >> 6;
    if ((tid & 63) == 0) { red[0][wave] = facc; red[1][wave] = bacc; red[2][wave] = iacc; red[3][wave] = pacc; }
    __syncthreads();
    if (tid == 0) {
        float f = 0, b = 0, i2 = 0, pp = 0;
        for (int w = 0; w < 4; ++w) { f += red[0][w]; b += red[1][w]; i2 += red[2][w]; pp += red[3][w]; }
        atomicAdd(&acc[0], f);
        atomicAdd(&acc[1], b);
        atomicAdd(&acc[2 + s], i2);
        atomicAdd(&acc[18 + s], pp);
    }
}

__global__ void final_kernel(const float* __restrict__ acc, const float* __restrict__ lv,
                             float* __restrict__ out) {
    if (threadIdx.x == 0) {
        float focal = acc[0] / NTOT_F;
        float bnd   = acc[1] / NTOT_F;
        float dsum = 0.f, isum = 0.f;
        for (int s = 0; s < NSAMP; ++s) {
            float inter = acc[2 + s];
            float tot   = acc[18 + s];
            dsum += (2.f * inter + 1e-6f) / (tot + 1e-6f);
            isum += (inter + 1e-6f) / (tot - inter + 1e-6f);
        }
        float dice = 1.f - dsum / 16.f;
        float iou  = 1.f - isum / 16.f;
        float l0 = lv[0], l1 = lv[1], l2 = lv[2], l3 = lv[3];
        float total = expf(-l0) * focal + l0 + expf(-l1) * dice + l1
                    + expf(-l2) * bnd  + l2 + expf(-l3) * iou  + l3;
        out[0] = total; out[1] = focal; out[2] = dice; out[3] = bnd; out[4] = iou;
    }
}

extern "C" void kernel_launch(void* const* d_in, const int* in_sizes, int n_in,
                              void* d_out, int out_size, void* d_ws, size_t ws_size,
                              hipStream_t stream) {
    const float* pred = (const float*)d_in[0];
    const int*   tg   = (const int*)d_in[1];
    const float* lv   = (const float*)d_in[2];
    float* out = (float*)d_out;
    char* ws = (char*)d_ws;
    float* acc      = (float*)ws;
    int*   flags    = (int*)(ws + 512);
    int*   blkflags = (int*)(ws + 1024);
    float* stripmax = (float*)(ws + OFF_SMAX);
    float* Llast    = (float*)(ws + OFF_LLAST);
    float* bounds   = (float*)(ws + OFF_BOUNDS);
    float* dA       = (float*)(ws + OFF_DA);
    float* dB       = (float*)(ws + OFF_DB);

    hipMemsetAsync(ws, 0, 512, stream);
    seed_kernel<<<NSAMP * HDIM, 128, 0, stream>>>(tg, dA, blkflags);
    flagreduce_kernel<<<NSAMP, 64, 0, stream>>>(blkflags, flags);
    // pass 1 (top-down)
    strip1a_kernel<<<NSAMP * NSTRIP, 64, 0, stream>>>(tg, dA, flags, Llast);
    bounds_kernel<<<NSAMP, 64, 0, stream>>>(Llast, bounds);
    strip3a_kernel<<<NSAMP * NSTRIP, 64, 0, stream>>>(tg, dA, flags, bounds, dB);
    // pass 2 (bottom-up, flipped) — Llast/bounds buffers reused
    strip1b_kernel<<<NSAMP * NSTRIP, 64, 0, stream>>>(dB, Llast);
    bounds_kernel<<<NSAMP, 64, 0, stream>>>(Llast, bounds);
    strip3b_kernel<<<NSAMP * NSTRIP, 64, 0, stream>>>(dB, bounds, dA, stripmax);
    maxred_kernel<<<NSAMP, 64, 0, stream>>>(stripmax, acc);
    loss_kernel<<<NSAMP * 32, 256, 0, stream>>>(pred, tg, dA, flags, acc);
    final_kernel<<<1, 64, 0, stream>>>(acc, lv, out);
}